// Round 2
// baseline (32.888 us; speedup 1.0000x reference)
//
#include <hip/hip_runtime.h>

// Lucas-Kanade optical flow, fused single kernel, LDS-vectorized.
// Input:  image_prev, image_next  (1,1,2048,2048) fp32
// Output: (1,2,2048,2048) fp32  -> u at [0:H*W], v at [H*W:2*H*W]

#define IMG_H 2048
#define IMG_W 2048
#define TW 32          // tile width  (output cols per block)
#define TH 64          // tile height (output rows per block)
#define LDSW 36        // cols 0..31 interior, 32 = right edge, 34 = left edge, pad to 36

// Block FMA contraction: the reference's det/numerators cancel catastrophically;
// fused product+add there changes u by >> threshold (proven in round 0).
__device__ __forceinline__ float mulnf(float a, float b) {
    float t = a * b;
    asm("" : "+v"(t));
    return t;
}

__global__ __launch_bounds__(256)
void lk_flow_kernel(const float* __restrict__ prev,
                    const float* __restrict__ next,
                    float* __restrict__ out) {
    // LDS col c holds res at image col c0+c (c=32: right halo col, c=34: left halo col c0-1)
    __shared__ __align__(16) float srx[TH + 2][LDSW];
    __shared__ __align__(16) float sry[TH + 2][LDSW];
    __shared__ __align__(16) float srt[TH + 2][LDSW];

    const int r0 = blockIdx.y * TH;
    const int c0 = blockIdx.x * TW;
    const int tid = threadIdx.y * 8 + threadIdx.x;

    // ---- Phase A (interior): res for image cols c0..c0+31 in 4-col chunks ----
    // chunk (hr, ch): res rows a=r0-1+hr, cols b..b+3, b = c0+4*ch (16B aligned)
    for (int t = tid; t < (TH + 2) * 8; t += 256) {
        const int hr = t >> 3;
        const int ch = t & 7;
        const int a  = r0 - 1 + hr;
        const int b  = c0 + ch * 4;
        float rx[4], ry[4], rt[4];
        if (a >= 0 && a < IMG_H) {
            const int a1 = (a + 1 == IMG_H) ? (IMG_H - 2) : (a + 1);  // reflect (after)
            const int b4 = (b + 4 == IMG_W) ? (IMG_W - 2) : (b + 4);  // reflect (after)
            const float4 P0 = *reinterpret_cast<const float4*>(&prev[(size_t)a  * IMG_W + b]);
            const float4 P1 = *reinterpret_cast<const float4*>(&prev[(size_t)a1 * IMG_W + b]);
            const float4 Q0 = *reinterpret_cast<const float4*>(&next[(size_t)a  * IMG_W + b]);
            const float4 Q1 = *reinterpret_cast<const float4*>(&next[(size_t)a1 * IMG_W + b]);
            const float p0[5] = {P0.x, P0.y, P0.z, P0.w, prev[(size_t)a  * IMG_W + b4]};
            const float p1[5] = {P1.x, P1.y, P1.z, P1.w, prev[(size_t)a1 * IMG_W + b4]};
            const float q0[5] = {Q0.x, Q0.y, Q0.z, Q0.w, next[(size_t)a  * IMG_W + b4]};
            const float q1[5] = {Q1.x, Q1.y, Q1.z, Q1.w, next[(size_t)a1 * IMG_W + b4]};
            #pragma unroll
            for (int q = 0; q < 4; ++q) {
                // exact left-to-right order as the reference elementwise exprs
                const float gxp = -p0[q] + p0[q+1] - p1[q] + p1[q+1];
                const float gxq = -q0[q] + q0[q+1] - q1[q] + q1[q+1];
                const float gyp = -p0[q] - p0[q+1] + p1[q] + p1[q+1];
                const float gyq = -q0[q] - q0[q+1] + q1[q] + q1[q+1];
                const float gsp =  p0[q] + p0[q+1] + p1[q] + p1[q+1];
                const float gsq =  q0[q] + q0[q+1] + q1[q] + q1[q+1];
                rx[q] = 0.5f * (gxp + gxq);
                ry[q] = 0.5f * (gyp + gyq);
                rt[q] = 0.5f * (-gsp + gsq);
            }
        } else {
            #pragma unroll
            for (int q = 0; q < 4; ++q) { rx[q] = 0.f; ry[q] = 0.f; rt[q] = 0.f; }
        }
        const int lc = ch * 4;
        #pragma unroll
        for (int q = 0; q < 4; ++q) {
            srx[hr][lc + q] = rx[q];
            sry[hr][lc + q] = ry[q];
            srt[hr][lc + q] = rt[q];
        }
    }

    // ---- Phase A (edges): image col c0-1 -> LDS col 34, image col c0+32 -> LDS col 32
    for (int t = tid; t < (TH + 2) * 2; t += 256) {
        const int hr = t >> 1;
        const int e  = t & 1;
        const int a  = r0 - 1 + hr;
        const int bc = e ? (c0 + TW) : (c0 - 1);
        const int lc = e ? TW : 34;
        float rx = 0.f, ry = 0.f, rt = 0.f;
        if (a >= 0 && a < IMG_H && bc >= 0 && bc < IMG_W) {
            const int a1 = (a + 1 == IMG_H) ? (IMG_H - 2) : (a + 1);
            const int b1 = (bc + 1 == IMG_W) ? (IMG_W - 2) : (bc + 1);
            const float p00 = prev[(size_t)a  * IMG_W + bc];
            const float p01 = prev[(size_t)a  * IMG_W + b1];
            const float p10 = prev[(size_t)a1 * IMG_W + bc];
            const float p11 = prev[(size_t)a1 * IMG_W + b1];
            const float q00 = next[(size_t)a  * IMG_W + bc];
            const float q01 = next[(size_t)a  * IMG_W + b1];
            const float q10 = next[(size_t)a1 * IMG_W + bc];
            const float q11 = next[(size_t)a1 * IMG_W + b1];
            const float gxp = -p00 + p01 - p10 + p11;
            const float gxq = -q00 + q01 - q10 + q11;
            const float gyp = -p00 - p01 + p10 + p11;
            const float gyq = -q00 - q01 + q10 + q11;
            const float gsp =  p00 + p01 + p10 + p11;
            const float gsq =  q00 + q01 + q10 + q11;
            rx = 0.5f * (gxp + gxq);
            ry = 0.5f * (gyp + gyq);
            rt = 0.5f * (-gsp + gsq);
        }
        srx[hr][lc] = rx; sry[hr][lc] = ry; srt[hr][lc] = rt;
    }

    __syncthreads();

    // ---- Phase B: each thread -> 2 output rows x 4 output cols ----
    const int cx  = threadIdx.x;           // 0..7: cols jb..jb+3, jb = 4*cx
    const int ty  = threadIdx.y;           // 0..31: rows 2*ty, 2*ty+1
    const int il0 = ty * 2;
    const int jb  = cx * 4;
    const int cm1 = (cx == 0) ? 34 : (jb - 1);   // LDS col of res col (c0+jb-1)

    float acc[2][4][5];
    #pragma unroll
    for (int r = 0; r < 2; ++r)
        #pragma unroll
        for (int q = 0; q < 4; ++q)
            #pragma unroll
            for (int p = 0; p < 5; ++p) acc[r][q][p] = 0.f;

    #pragma unroll
    for (int rr = 0; rr < 4; ++rr) {
        const int hr = il0 + rr;   // res row r0-1+hr
        const float4 vx = *reinterpret_cast<const float4*>(&srx[hr][jb]);
        const float4 vy = *reinterpret_cast<const float4*>(&sry[hr][jb]);
        const float4 vt = *reinterpret_cast<const float4*>(&srt[hr][jb]);
        // X[k] = res col (c0 + jb - 1 + k)
        const float X[6] = { srx[hr][cm1], vx.x, vx.y, vx.z, vx.w, srx[hr][jb + 4] };
        const float Y[6] = { sry[hr][cm1], vy.x, vy.y, vy.z, vy.w, sry[hr][jb + 4] };
        const float T[6] = { srt[hr][cm1], vt.x, vt.y, vt.z, vt.w, srt[hr][jb + 4] };
        float pxx[6], pyy[6], pxy[6], pxt[6], pyt[6];
        #pragma unroll
        for (int k = 0; k < 6; ++k) {
            pxx[k] = mulnf(X[k], X[k]);
            pyy[k] = mulnf(Y[k], Y[k]);
            pxy[k] = mulnf(X[k], Y[k]);
            pxt[k] = mulnf(T[k], X[k]);
            pyt[k] = mulnf(T[k], Y[k]);
        }
        // output row r (local il0+r) uses res rows il0+r .. il0+r+2
        #pragma unroll
        for (int r = 0; r < 2; ++r) {
            if (rr >= r && rr <= r + 2) {   // compile-time after unroll
                #pragma unroll
                for (int q = 0; q < 4; ++q) {
                    #pragma unroll
                    for (int dc = 0; dc < 3; ++dc) {
                        // exact reference box3 order: dr outer (rr asc), dc inner
                        acc[r][q][0] += pxx[q + dc];
                        acc[r][q][1] += pyy[q + dc];
                        acc[r][q][2] += pxy[q + dc];
                        acc[r][q][3] += pxt[q + dc];
                        acc[r][q][4] += pyt[q + dc];
                    }
                }
            }
        }
    }

    #pragma unroll
    for (int r = 0; r < 2; ++r) {
        const int i = r0 + il0 + r;
        float uo[4], vo[4];
        #pragma unroll
        for (int q = 0; q < 4; ++q) {
            const float Sxx = acc[r][q][0], Syy = acc[r][q][1], Sxy = acc[r][q][2];
            const float Sxt = acc[r][q][3], Syt = acc[r][q][4];
            const float t1 = mulnf(Sxx, Syy);
            const float t2 = mulnf(Sxy, Sxy);
            const float det = t1 - t2;
            float u = 0.f, v = 0.f;
            if (det != 0.f) {
                const float inv = 1.0f / det;   // one IEEE divide
                const float n1 = mulnf(Syy, Sxt) - mulnf(Sxy, Syt);
                const float n2 = mulnf(Sxx, Syt) - mulnf(Sxy, Sxt);
                u = n1 * inv;
                v = n2 * inv;
            }
            const int j = c0 + jb + q;
            if (i == 0 || j == 0) { u = 0.f; v = 0.f; }  // reference zeroes row0/col0
            uo[q] = u; vo[q] = v;
        }
        float4 U = {uo[0], uo[1], uo[2], uo[3]};
        float4 V = {vo[0], vo[1], vo[2], vo[3]};
        *reinterpret_cast<float4*>(&out[(size_t)i * IMG_W + (c0 + jb)]) = U;
        *reinterpret_cast<float4*>(&out[(size_t)(IMG_H + i) * IMG_W + (c0 + jb)]) = V;
    }
}

extern "C" void kernel_launch(void* const* d_in, const int* in_sizes, int n_in,
                              void* d_out, int out_size, void* d_ws, size_t ws_size,
                              hipStream_t stream) {
    const float* prev = (const float*)d_in[0];
    const float* next = (const float*)d_in[1];
    float* out = (float*)d_out;
    dim3 grid(IMG_W / TW, IMG_H / TH);   // 64 x 32
    dim3 block(8, 32);
    lk_flow_kernel<<<grid, block, 0, stream>>>(prev, next, out);
}